// Round 1
// baseline (635.190 us; speedup 1.0000x reference)
//
#include <hip/hip_runtime.h>
#include <hip/hip_bf16.h>
#include <stdint.h>

// Shapes (hard-coded for this problem)
#define T_  4
#define B_  64
#define C_  384
#define N_  196        // H*W = 14*14
#define NH  8
#define DH  48
#define TB_ (T_*B_)          // 256
#define R_  (T_*B_*N_)       // 50176 pixels total
#define NW  12               // 384 bits -> 12 u32 words per pixel
#define SBLK 392             // stats partial blocks; 50176 = 392*128
#define ROWS_PER 128

// ---------------------------------------------------------------------------
// K0: transpose weight W[o][c] -> WT[c][o]  (column access for sparse conv)
__global__ void transpose_w(const float* __restrict__ src, float* __restrict__ dst){
    int idx = blockIdx.x*256 + threadIdx.x;        // idx = c*C_ + o
    if (idx >= C_*C_) return;
    int o = idx % C_, c = idx / C_;
    dst[idx] = src[o*C_ + c];
}

// ---------------------------------------------------------------------------
// K1: pre-LIF on raw x -> spike bitmask [t][b][n][12 words]
// block handles one (b, word w); threads = n
__global__ __launch_bounds__(256) void pre_lif(const float* __restrict__ x,
                                               uint32_t* __restrict__ maskXS){
    int b = blockIdx.x / NW;
    int w = blockIdx.x % NW;
    int n = threadIdx.x;
    if (n >= N_) return;
    float v[32];
#pragma unroll
    for (int j=0;j<32;j++) v[j] = 0.f;
#pragma unroll
    for (int t=0;t<T_;t++){
        uint32_t word = 0;
#pragma unroll
        for (int j=0;j<32;j++){
            int c = w*32 + j;
            float xv = x[((size_t)(t*B_+b)*C_ + c)*N_ + n];
            v[j] = 0.5f*(v[j] + xv);          // v += (x - v)/tau, tau=2
            if (v[j] >= 1.0f){ word |= (1u<<j); v[j] = 0.f; }
        }
        maskXS[((size_t)(t*B_+b)*N_ + n)*NW + w] = word;
    }
}

// ---------------------------------------------------------------------------
// K2: sparse 1x1 conv: Y[pix][o] = sum over active c of WT[c][o]
// one wave per pixel; lane covers o = i*64+lane, i=0..5
__global__ __launch_bounds__(256) void conv_spikes(const uint32_t* __restrict__ mask,
                                                   const float* __restrict__ WT,
                                                   float* __restrict__ Y){
    int wave = threadIdx.x >> 6, lane = threadIdx.x & 63;
    int pix  = blockIdx.x*4 + wave;                 // 12544*4 = 50176 exactly
    const uint32_t* mw = mask + (size_t)pix*NW;
    float y[6];
#pragma unroll
    for (int i=0;i<6;i++) y[i] = 0.f;
    for (int w=0; w<NW; w++){
        uint32_t bits = mw[w];                      // uniform across the wave
        while (bits){
            int c = (w<<5) + __builtin_ctz(bits);
            bits &= bits - 1;
            const float* col = WT + c*C_ + lane;
#pragma unroll
            for (int i=0;i<6;i++) y[i] += col[i*64];
        }
    }
    float* yo = Y + (size_t)pix*C_ + lane;
#pragma unroll
    for (int i=0;i<6;i++) yo[i*64] = y[i];
}

// ---------------------------------------------------------------------------
// K3: BN partial stats (sum, sumsq) per channel
__global__ __launch_bounds__(384) void stats_partial(const float* __restrict__ Y,
                                                     float* __restrict__ p1,
                                                     float* __restrict__ p2){
    int o = threadIdx.x;
    int blk = blockIdx.x;
    const float* base = Y + (size_t)blk*ROWS_PER*C_ + o;
    float s1 = 0.f, s2 = 0.f;
    for (int r=0;r<ROWS_PER;r++){
        float v = base[(size_t)r*C_];
        s1 += v; s2 += v*v;
    }
    p1[blk*C_ + o] = s1;
    p2[blk*C_ + o] = s2;
}

// K4: finalize BN -> fused scale/shift
__global__ __launch_bounds__(384) void stats_final(const float* __restrict__ p1,
                                                   const float* __restrict__ p2,
                                                   const float* __restrict__ g,
                                                   const float* __restrict__ bta,
                                                   float* __restrict__ scale,
                                                   float* __restrict__ shift){
    int o = threadIdx.x;
    float s1 = 0.f, s2 = 0.f;
    for (int b=0;b<SBLK;b++){ s1 += p1[b*C_+o]; s2 += p2[b*C_+o]; }
    float m   = s1 / (float)R_;
    float var = s2 / (float)R_ - m*m;
    float sc  = g[o] / sqrtf(var + 1e-5f);
    scale[o] = sc;
    shift[o] = bta[o] - m*sc;
}

// ---------------------------------------------------------------------------
// K5: LIF over normalized y, pack spikes into bitmask via ballot
// block = one (b,n) pixel; 384 threads = channels; loop t inside
__global__ __launch_bounds__(384) void lif_pack(const float* __restrict__ Y,
                                                const float* __restrict__ scale,
                                                const float* __restrict__ shift,
                                                uint32_t* __restrict__ maskOut,
                                                float vth, int affine){
    int pix0 = blockIdx.x;            // b*N_ + n
    int o = threadIdx.x;
    float sc = affine ? scale[o] : 1.f;
    float sh = affine ? shift[o] : 0.f;
    int w = o >> 6, lane = o & 63;
    float v = 0.f;
#pragma unroll
    for (int t=0;t<T_;t++){
        size_t pix = (size_t)t*B_*N_ + pix0;
        float y = Y[pix*C_ + o]*sc + sh;
        v = 0.5f*(v + y);
        int s = (v >= vth);
        unsigned long long bal = __ballot(s);
        if (s) v = 0.f;
        if (lane == 0){
            maskOut[pix*NW + 2*w    ] = (uint32_t)bal;
            maskOut[pix*NW + 2*w + 1] = (uint32_t)(bal >> 32);
        }
    }
}

// ---------------------------------------------------------------------------
// K6: spiking attention, exact integer path.
// grid = (t*B+b)*8 + h ; S[n,m] = popc(q48[n]&k48[m]); O = 0.125*(S@v)
__global__ __launch_bounds__(256) void attention(const uint32_t* __restrict__ mq,
                                                 const uint32_t* __restrict__ mk,
                                                 const uint32_t* __restrict__ mv,
                                                 float* __restrict__ O){
    __shared__ unsigned long long kS[N_];
    __shared__ unsigned long long vT[DH][4];        // per-d bitmask over m
    __shared__ uint32_t sRow[N_*51];                // u8 S values, 4-packed, stride 51 words

    int id = blockIdx.x;
    int h  = id & 7;
    int tb = id >> 3;
    int tid = threadIdx.x;
    int sw  = (h*DH) >> 5;          // start word
    int shf = (h*DH) & 31;          // 0 or 16

    unsigned long long q = 0, vv = 0;
    if (tid < N_){
        const uint32_t* pq = mq + ((size_t)tb*N_ + tid)*NW + sw;
        const uint32_t* pk = mk + ((size_t)tb*N_ + tid)*NW + sw;
        const uint32_t* pv = mv + ((size_t)tb*N_ + tid)*NW + sw;
        unsigned long long lo, hi;
        lo = pq[0]; hi = pq[1];
        q  = (shf ? ((lo>>16) | (hi<<16)) : (lo | (hi<<32))) & 0xFFFFFFFFFFFFULL;
        lo = pk[0]; hi = pk[1];
        kS[tid] = (shf ? ((lo>>16) | (hi<<16)) : (lo | (hi<<32))) & 0xFFFFFFFFFFFFULL;
        lo = pv[0]; hi = pv[1];
        vv = (shf ? ((lo>>16) | (hi<<16)) : (lo | (hi<<32))) & 0xFFFFFFFFFFFFULL;
    }
    // transpose v bits: vT[d] bit m = v[m] bit d  (ballot per wave)
    int wv = tid >> 6;
#pragma unroll 1
    for (int d=0; d<DH; d++){
        unsigned long long bal = __ballot((int)((vv>>d)&1ull));
        if ((tid & 63) == 0) vT[d][wv] = bal;
    }
    __syncthreads();

    if (tid < N_){
        // S row: 49 packed words of 4 u8 popcounts
        for (int g4=0; g4<49; g4++){
            uint32_t pk = 0;
#pragma unroll
            for (int j=0;j<4;j++){
                int m = g4*4 + j;
                uint32_t s = (uint32_t)__popcll(q & kS[m]);
                pk |= s << (8*j);
            }
            sRow[tid*51 + g4] = pk;
        }
    }
    __syncthreads();

    if (tid < N_){
        float* Op = O + ((size_t)tb*N_ + tid)*C_ + h*DH;
        const uint32_t* myRow = &sRow[tid*51];
        for (int d=0; d<DH; d++){
            int a = 0;
#pragma unroll
            for (int w4=0; w4<4; w4++){
                unsigned long long bb = vT[d][w4];   // uniform across lanes
                while (bb){
                    int m = (w4<<6) + __builtin_ctzll(bb);
                    bb &= bb - 1;
                    a += (int)((myRow[m>>2] >> ((m&3)*8)) & 0xFF);
                }
            }
            Op[d] = 0.125f * (float)a;
        }
    }
}

// ---------------------------------------------------------------------------
// K7: final BN-normalize + layout transform [pix][c] -> [t,b,c,n]
__global__ __launch_bounds__(256) void final_norm(const float* __restrict__ Yp,
                                                  const float* __restrict__ scale,
                                                  const float* __restrict__ shift,
                                                  float* __restrict__ out){
    size_t idx = (size_t)blockIdx.x*256 + threadIdx.x;   // output index [t,b,c,n]
    if (idx >= (size_t)R_*C_) return;
    int n  = (int)(idx % N_);
    int c  = (int)((idx / N_) % C_);
    int tb = (int)(idx / ((size_t)N_*C_));
    float y = Yp[((size_t)tb*N_ + n)*C_ + c];
    out[idx] = y*scale[c] + shift[c];
}

// ---------------------------------------------------------------------------
extern "C" void kernel_launch(void* const* d_in, const int* in_sizes, int n_in,
                              void* d_out, int out_size, void* d_ws, size_t ws_size,
                              hipStream_t stream) {
    const float* x  = (const float*)d_in[0];
    const float* Wq = (const float*)d_in[1];
    const float* Wk = (const float*)d_in[2];
    const float* Wv = (const float*)d_in[3];
    const float* Wp = (const float*)d_in[4];
    const float* gq = (const float*)d_in[5];
    const float* bq = (const float*)d_in[6];
    const float* gk = (const float*)d_in[7];
    const float* bk = (const float*)d_in[8];
    const float* gv = (const float*)d_in[9];
    const float* bv = (const float*)d_in[10];
    const float* gp = (const float*)d_in[11];
    const float* bp = (const float*)d_in[12];

    // workspace carve
    char* w = (char*)d_ws;
    size_t off = 0;
    float* Ybuf = (float*)(w + off);  off += (size_t)R_*C_*4;        // 77 MB (Y / O / Yp)
    uint32_t* maskXS = (uint32_t*)(w + off); off += (size_t)R_*NW*4; // 2.4 MB
    uint32_t* maskQ  = (uint32_t*)(w + off); off += (size_t)R_*NW*4;
    uint32_t* maskK  = (uint32_t*)(w + off); off += (size_t)R_*NW*4;
    uint32_t* maskV  = (uint32_t*)(w + off); off += (size_t)R_*NW*4;
    uint32_t* maskOL = (uint32_t*)(w + off); off += (size_t)R_*NW*4;
    float* WTq = (float*)(w + off); off += (size_t)C_*C_*4;
    float* WTk = (float*)(w + off); off += (size_t)C_*C_*4;
    float* WTv = (float*)(w + off); off += (size_t)C_*C_*4;
    float* WTp = (float*)(w + off); off += (size_t)C_*C_*4;
    float* part1 = (float*)(w + off); off += (size_t)SBLK*C_*4;
    float* part2 = (float*)(w + off); off += (size_t)SBLK*C_*4;
    float* scaleB = (float*)(w + off); off += C_*4;
    float* shiftB = (float*)(w + off); off += C_*4;

    int tgrid = (C_*C_ + 255)/256;
    transpose_w<<<tgrid,256,0,stream>>>(Wq, WTq);
    transpose_w<<<tgrid,256,0,stream>>>(Wk, WTk);
    transpose_w<<<tgrid,256,0,stream>>>(Wv, WTv);
    transpose_w<<<tgrid,256,0,stream>>>(Wp, WTp);

    pre_lif<<<B_*NW,256,0,stream>>>(x, maskXS);

    const float* Gs[3] = {gq, gk, gv};
    const float* Bs[3] = {bq, bk, bv};
    const float* WTs[3] = {WTq, WTk, WTv};
    uint32_t* Ms[3] = {maskQ, maskK, maskV};
    for (int i=0;i<3;i++){
        conv_spikes<<<R_/4,256,0,stream>>>(maskXS, WTs[i], Ybuf);
        stats_partial<<<SBLK,384,0,stream>>>(Ybuf, part1, part2);
        stats_final<<<1,384,0,stream>>>(part1, part2, Gs[i], Bs[i], scaleB, shiftB);
        lif_pack<<<B_*N_,384,0,stream>>>(Ybuf, scaleB, shiftB, Ms[i], 1.0f, 1);
    }

    attention<<<TB_*NH,256,0,stream>>>(maskQ, maskK, maskV, Ybuf);

    lif_pack<<<B_*N_,384,0,stream>>>(Ybuf, scaleB, shiftB, maskOL, 0.5f, 0);

    conv_spikes<<<R_/4,256,0,stream>>>(maskOL, WTp, Ybuf);
    stats_partial<<<SBLK,384,0,stream>>>(Ybuf, part1, part2);
    stats_final<<<1,384,0,stream>>>(part1, part2, gp, bp, scaleB, shiftB);

    final_norm<<<(int)(((size_t)R_*C_ + 255)/256),256,0,stream>>>(Ybuf, scaleB, shiftB, (float*)d_out);
}